// Round 3
// baseline (377.620 us; speedup 1.0000x reference)
//
#include <hip/hip_runtime.h>
#include <math.h>

// Problem constants (fixed by setup_inputs)
constexpr int Bsz   = 64;
constexpr int Mmel  = 80;
constexpr int Tout  = 2000;
constexpr int Tin   = 400;
constexpr int MEL_N  = Bsz * Mmel * Tout;   // 10,240,000
constexpr int GATE_N = Bsz * Tout;          // 128,000
constexpr int ROWS   = Bsz * Tout;          // 128,000 alignment rows
constexpr int TIN4   = Tin / 4;             // 100 float4 per row

constexpr float ATT_W = 0.1f;
constexpr float GA_W  = 0.1f;
// exp(-d^2 * 3.125) == exp2(d^2 * -3.125*log2(e))
constexpr float NEG_C = -3.125f * 1.44269504088896340736f;

constexpr int NBLK   = 2048;                // exactly 8 blocks/CU -> 32 waves/CU, single batch
constexpr int NTHR   = 256;
constexpr int NWAVES = NBLK * NTHR / 64;    // 8192

__device__ __forceinline__ float wave_reduce(float v) {
    #pragma unroll
    for (int off = 32; off > 0; off >>= 1)
        v += __shfl_down(v, off, 64);
    return v;
}

__device__ __forceinline__ double wave_reduce_d(double v) {
    #pragma unroll
    for (int off = 32; off > 0; off >>= 1)
        v += __shfl_down(v, off, 64);
    return v;
}

// Process one float4 of an alignment row. All-float compares (values integral,
// exact in fp32). Inactive tail lanes pass a==0 so att contribution is 0;
// ga mask is automatically false there (jf >= 400 >= il).
__device__ __forceinline__ void proc4(float4 a, float jb, float fi,
                                      float ilf, float olf, float sc,
                                      float& att_s, float& ga_s)
{
    const bool rv = fi < olf;               // irow < output_len
    const float av[4] = {a.x, a.y, a.z, a.w};
    #pragma unroll
    for (int k = 0; k < 4; ++k) {
        const float jf = jb + (float)k;
        att_s += (jf < fi) ? av[k] : 0.0f;  // jj < irow (strict)
        const float d = fmaf(-jf, sc, fi);  // fi - jf*scale
        const float e = exp2f(d * d * NEG_C);
        const float g = av[k] - av[k] * e;  // av*(1-e)
        ga_s += (rv && (jf < ilf)) ? g : 0.0f;
    }
}

__global__ __launch_bounds__(NTHR) void loss_main(
    const float* __restrict__ mel_out,
    const float* __restrict__ mel_post,
    const float* __restrict__ gate_out,
    const float* __restrict__ align,
    const float* __restrict__ mel_tgt,
    const float* __restrict__ gate_tgt,
    const int*   __restrict__ in_len,
    const int*   __restrict__ out_len,
    float4* __restrict__ partials)          // partials[blockIdx] = {mel, gate, att, ga}
{
    __shared__ float s_ilf[Bsz];
    __shared__ float s_olf[Bsz];
    __shared__ float s_sc[Bsz];
    if (threadIdx.x < Bsz) {
        const float il = (float)in_len[threadIdx.x];
        const float ol = (float)out_len[threadIdx.x];
        s_ilf[threadIdx.x] = il;
        s_olf[threadIdx.x] = ol;
        s_sc[threadIdx.x]  = ol / il;
    }
    __syncthreads();

    const int tid    = blockIdx.x * blockDim.x + threadIdx.x;
    const int stride = gridDim.x * blockDim.x;   // 524,288

    float mel_s = 0.f, gate_s = 0.f, att_s = 0.f, ga_s = 0.f;

    // ---- Mel L1 (decoder + postnet), unroll x2: 6 x 1KB wave-loads in flight ----
    {
        const float4* a4 = (const float4*)mel_out;
        const float4* p4 = (const float4*)mel_post;
        const float4* t4 = (const float4*)mel_tgt;
        const int n4 = MEL_N / 4;                // 2,560,000
        int i = tid;
        for (; i + stride < n4; i += 2 * stride) {
            const int i1 = i + stride;
            float4 a0 = a4[i],  a1 = a4[i1];
            float4 p0 = p4[i],  p1 = p4[i1];
            float4 t0 = t4[i],  t1 = t4[i1];
            mel_s += fabsf(a0.x - t0.x) + fabsf(a0.y - t0.y) + fabsf(a0.z - t0.z) + fabsf(a0.w - t0.w);
            mel_s += fabsf(p0.x - t0.x) + fabsf(p0.y - t0.y) + fabsf(p0.z - t0.z) + fabsf(p0.w - t0.w);
            mel_s += fabsf(a1.x - t1.x) + fabsf(a1.y - t1.y) + fabsf(a1.z - t1.z) + fabsf(a1.w - t1.w);
            mel_s += fabsf(p1.x - t1.x) + fabsf(p1.y - t1.y) + fabsf(p1.z - t1.z) + fabsf(p1.w - t1.w);
        }
        for (; i < n4; i += stride) {
            float4 a = a4[i], p = p4[i], t = t4[i];
            mel_s += fabsf(a.x - t.x) + fabsf(a.y - t.y) + fabsf(a.z - t.z) + fabsf(a.w - t.w);
            mel_s += fabsf(p.x - t.x) + fabsf(p.y - t.y) + fabsf(p.z - t.z) + fabsf(p.w - t.w);
        }
    }

    // ---- Gate BCE-with-logits (tiny; only tids < 32000 iterate) ----
    {
        const float4* x4 = (const float4*)gate_out;
        const float4* z4 = (const float4*)gate_tgt;
        const int n4 = GATE_N / 4;
        for (int i = tid; i < n4; i += stride) {
            float4 x = x4[i], z = z4[i];
            gate_s += fmaxf(x.x, 0.f) - x.x * z.x + log1pf(expf(-fabsf(x.x)));
            gate_s += fmaxf(x.y, 0.f) - x.y * z.y + log1pf(expf(-fabsf(x.y)));
            gate_s += fmaxf(x.z, 0.f) - x.z * z.z + log1pf(expf(-fabsf(x.z)));
            gate_s += fmaxf(x.w, 0.f) - x.w * z.w + log1pf(expf(-fabsf(x.w)));
        }
    }

    // ---- Alignment terms: one 1600B row per wave per step, unroll x2 rows ----
    // Row index math (magic div) once per row instead of per float4; lane
    // covers float4 idx {lane, lane+64} (second masked to lane<36: 100/row).
    {
        const float4* al4 = (const float4*)align;
        const int wv   = (blockIdx.x << 2) | (threadIdx.x >> 6);   // 0..8191
        const int lane = threadIdx.x & 63;
        const float jb0 = (float)(4 * lane);
        const float jb1 = jb0 + 256.0f;
        const bool tail = lane < (TIN4 - 64);                      // lane < 36

        int r = wv;
        for (; r + NWAVES < ROWS; r += 2 * NWAVES) {
            const int r1 = r + NWAVES;
            const int b0 = r  / Tout;
            const int b1 = r1 / Tout;
            const int ir0 = r  - b0 * Tout;
            const int ir1 = r1 - b1 * Tout;
            const float4* rp0 = al4 + (size_t)r  * TIN4;
            const float4* rp1 = al4 + (size_t)r1 * TIN4;
            // 4 loads issued before any consume
            float4 a00 = rp0[lane];
            float4 a10 = rp1[lane];
            float4 a01 = make_float4(0.f, 0.f, 0.f, 0.f);
            float4 a11 = make_float4(0.f, 0.f, 0.f, 0.f);
            if (tail) a01 = rp0[lane + 64];
            if (tail) a11 = rp1[lane + 64];

            const float fi0 = (float)ir0, fi1 = (float)ir1;
            const float il0 = s_ilf[b0], ol0 = s_olf[b0], sc0 = s_sc[b0];
            const float il1 = s_ilf[b1], ol1 = s_olf[b1], sc1 = s_sc[b1];

            proc4(a00, jb0, fi0, il0, ol0, sc0, att_s, ga_s);
            proc4(a01, jb1, fi0, il0, ol0, sc0, att_s, ga_s);
            proc4(a10, jb0, fi1, il1, ol1, sc1, att_s, ga_s);
            proc4(a11, jb1, fi1, il1, ol1, sc1, att_s, ga_s);
        }
        for (; r < ROWS; r += NWAVES) {
            const int b  = r / Tout;
            const int ir = r - b * Tout;
            const float4* rp = al4 + (size_t)r * TIN4;
            float4 a0 = rp[lane];
            float4 a1 = make_float4(0.f, 0.f, 0.f, 0.f);
            if (tail) a1 = rp[lane + 64];
            const float fi = (float)ir;
            proc4(a0, jb0, fi, s_ilf[b], s_olf[b], s_sc[b], att_s, ga_s);
            proc4(a1, jb1, fi, s_ilf[b], s_olf[b], s_sc[b], att_s, ga_s);
        }
    }

    // ---- Block reduction: wave shuffle -> LDS -> one partial write per block ----
    __shared__ float smem[NTHR / 64][4];
    const int lane = threadIdx.x & 63;
    const int wid  = threadIdx.x >> 6;

    mel_s  = wave_reduce(mel_s);
    gate_s = wave_reduce(gate_s);
    att_s  = wave_reduce(att_s);
    ga_s   = wave_reduce(ga_s);
    if (lane == 0) {
        smem[wid][0] = mel_s;
        smem[wid][1] = gate_s;
        smem[wid][2] = att_s;
        smem[wid][3] = ga_s;
    }
    __syncthreads();
    if (threadIdx.x == 0) {
        float m = 0.f, g = 0.f, at = 0.f, ga = 0.f;
        #pragma unroll
        for (int w = 0; w < NTHR / 64; ++w) {
            m  += smem[w][0];
            g  += smem[w][1];
            at += smem[w][2];
            ga += smem[w][3];
        }
        partials[blockIdx.x] = make_float4(m, g, at, ga);
    }
}

__global__ __launch_bounds__(512) void loss_final(
    const float4* __restrict__ partials, float* __restrict__ out)
{
    double m = 0.0, g = 0.0, at = 0.0, ga = 0.0;
    for (int i = threadIdx.x; i < NBLK; i += 512) {
        float4 p = partials[i];
        m += p.x; g += p.y; at += p.z; ga += p.w;
    }
    m  = wave_reduce_d(m);
    g  = wave_reduce_d(g);
    at = wave_reduce_d(at);
    ga = wave_reduce_d(ga);

    __shared__ double smem[8][4];
    const int lane = threadIdx.x & 63;
    const int wid  = threadIdx.x >> 6;
    if (lane == 0) {
        smem[wid][0] = m; smem[wid][1] = g; smem[wid][2] = at; smem[wid][3] = ga;
    }
    __syncthreads();
    if (threadIdx.x == 0) {
        double ms = 0, gs = 0, ats = 0, gas = 0;
        #pragma unroll
        for (int w = 0; w < 8; ++w) {
            ms += smem[w][0]; gs += smem[w][1]; ats += smem[w][2]; gas += smem[w][3];
        }
        const double mel  = ms  / (double)MEL_N;
        const double gate = gs  / (double)GATE_N;
        const double att  = ats / (double)Bsz;
        const double gav  = gas / (double)Bsz;
        const double total = mel + gate + (double)ATT_W * att + (double)GA_W * gav;
        out[0] = (float)total;
        out[1] = (float)mel;
        out[2] = (float)gate;
        out[3] = (float)att;
        out[4] = (float)gav;
    }
}

extern "C" void kernel_launch(void* const* d_in, const int* in_sizes, int n_in,
                              void* d_out, int out_size, void* d_ws, size_t ws_size,
                              hipStream_t stream) {
    const float* mel_out  = (const float*)d_in[0];
    const float* mel_post = (const float*)d_in[1];
    const float* gate_out = (const float*)d_in[2];
    const float* align    = (const float*)d_in[3];
    const float* mel_tgt  = (const float*)d_in[4];
    const float* gate_tgt = (const float*)d_in[5];
    const int*   in_len   = (const int*)d_in[6];
    const int*   out_len  = (const int*)d_in[7];

    float4* partials = (float4*)d_ws;       // NBLK * 16 B = 32 KiB; every block overwrites its slot

    loss_main<<<NBLK, NTHR, 0, stream>>>(mel_out, mel_post, gate_out, align,
                                         mel_tgt, gate_tgt, in_len, out_len, partials);
    loss_final<<<1, 512, 0, stream>>>(partials, (float*)d_out);
}